// Round 1
// 422.215 us; speedup vs baseline: 1.0112x; 1.0112x over previous
//
#include <hip/hip_runtime.h>
#include <math.h>

// ---------------------------------------------------------------------------
// AttnBlock: per-edge radial-MLP attention logits + segment softmax over dst.
//
// Structure (3 stream ops):
//   memset ssum[N]=0 (double)
//   K1 edge:  dot[e] -> d_out (fp32), atomicAdd ssum[v[e]] += exp((double)dot)
//   K2 norm:  d_out[e] = (float)( exp((double)dot) / ssum[v[e]] )
//
// fp64 exp/sum/divide replaces the per-node max pass: exp range +-709 in
// double strictly dominates the achievable |dot| (LN bounds the MLP output),
// so this is exactly the max-stabilized softmax without the extra E-sweep.
//
// R4 change (this round): the per-edge wj tensors (wj11: 27 floats at a
// 108B lane stride, wj01/wj10: 3 floats at 12B stride) were fully
// uncoalesced -- each global_load_dword split into ~64 transactions/wave
// (~2000 transactions/wave vs ~40 ideal; FETCH_SIZE stayed near-ideal only
// because L2 absorbed the re-reads). Now each block stages its 256-edge
// slab of wj01/wj10/wj11 into LDS with coalesced float4 loads; threads
// read their own row at stride 27/3 floats (odd stride -> 2 lanes/bank =
// conflict-free). f0/f1 gathers made explicit float2 (8B-aligned).
// ---------------------------------------------------------------------------

#define TPB 256

typedef float f2 __attribute__((ext_vector_type(2)));
typedef float f4 __attribute__((ext_vector_type(4)));

static __device__ __forceinline__ f2 fma2(f2 a, f2 b, f2 c) {
    return __builtin_elementwise_fma(a, b, c);
}
static __device__ __forceinline__ f2 splat(float x) {
    f2 r;
    r.x = x;
    r.y = x;
    return r;
}
static __device__ __forceinline__ float get16(const f2* h, int c) {
    return (c & 1) ? h[c >> 1].y : h[c >> 1].x;
}

// LayerNorm(16) + ReLU over h[8] (packed pairs). g/be are f2-aligned.
static __device__ __forceinline__ void ln_relu16(f2* h, const float* __restrict__ g,
                                                 const float* __restrict__ be) {
    const f2* g2 = (const f2*)g;
    const f2* be2 = (const f2*)be;
    f2 s = h[0] + h[1] + h[2] + h[3] + h[4] + h[5] + h[6] + h[7];
    const float mu = (s.x + s.y) * 0.0625f;
    const f2 mu2 = splat(mu);
    f2 vs = splat(0.f);
#pragma unroll
    for (int i = 0; i < 8; ++i) {
        f2 d = h[i] - mu2;
        vs = fma2(d, d, vs);
    }
    const float var = (vs.x + vs.y) * 0.0625f;
    const f2 r2 = splat(rsqrtf(var + 1e-5f));
    const f2 zero = splat(0.f);
#pragma unroll
    for (int i = 0; i < 8; ++i) {
        f2 t = (h[i] - mu2) * r2;
        h[i] = __builtin_elementwise_max(fma2(t, g2[i], be2[i]), zero);
    }
}

// layers 1..2 of a radial MLP: vec(3) -> 16 -> LN/relu -> 16 -> LN/relu
static __device__ __forceinline__ void radial_h2(
    float v0, float v1, float v2, const float* __restrict__ W1,
    const float* __restrict__ b1, const float* __restrict__ g1,
    const float* __restrict__ be1, const float* __restrict__ W2,
    const float* __restrict__ b2, const float* __restrict__ g2,
    const float* __restrict__ be2, f2* h2) {
    const f2* W1r0 = (const f2*)W1;
    const f2* W1r1 = (const f2*)(W1 + 16);
    const f2* W1r2 = (const f2*)(W1 + 32);
    const f2* b1v = (const f2*)b1;
    const f2 a = splat(v0), b = splat(v1), c = splat(v2);
    f2 h[8];
#pragma unroll
    for (int j = 0; j < 8; ++j)
        h[j] = fma2(a, W1r0[j], fma2(b, W1r1[j], fma2(c, W1r2[j], b1v[j])));
    ln_relu16(h, g1, be1);

    const f2* b2v = (const f2*)b2;
#pragma unroll
    for (int j = 0; j < 8; ++j) h2[j] = b2v[j];
#pragma unroll
    for (int c16 = 0; c16 < 16; ++c16) {
        const f2 hc = splat(get16(h, c16));
        const f2* row = (const f2*)(W2 + c16 * 16);
#pragma unroll
        for (int j = 0; j < 8; ++j) h2[j] = fma2(hc, row[j], h2[j]);
    }
    ln_relu16(h2, g2, be2);
}

// layer3 for OUT=4: p0={R0(o0i0),R1(o0i1)}, p1={R2(o1i0),R3(o1i1)}
static __device__ __forceinline__ void layer3_4(const f2* h2,
                                                const float* __restrict__ W3,
                                                const float* __restrict__ b3,
                                                f2& p0, f2& p1) {
    p0 = *(const f2*)(b3);
    p1 = *(const f2*)(b3 + 2);
#pragma unroll
    for (int c = 0; c < 16; ++c) {
        const f2 hc = splat(get16(h2, c));
        p0 = fma2(hc, *(const f2*)(W3 + c * 4), p0);
        p1 = fma2(hc, *(const f2*)(W3 + c * 4 + 2), p1);
    }
}

__global__ __launch_bounds__(TPB, 2) void edge_kernel(
    const float* __restrict__ f0, const float* __restrict__ f1,
    const float* __restrict__ dist, const int* __restrict__ u,
    const int* __restrict__ v, const float* __restrict__ wq,
    const float* __restrict__ wj00, const float* __restrict__ wj01,
    const float* __restrict__ wj10, const float* __restrict__ wj11,
    const float* __restrict__ rW1, const float* __restrict__ rb1,
    const float* __restrict__ g1, const float* __restrict__ be1,
    const float* __restrict__ rW2, const float* __restrict__ rb2,
    const float* __restrict__ g2, const float* __restrict__ be2,
    const float* __restrict__ W3_00, const float* __restrict__ b3_00,
    const float* __restrict__ W3_01, const float* __restrict__ b3_01,
    const float* __restrict__ W3_10, const float* __restrict__ b3_10,
    const float* __restrict__ W3_11, const float* __restrict__ b3_11,
    float* __restrict__ out, double* __restrict__ ssum, int E) {
    // coalesced staging of the per-edge wj tensors for this block's slab
    __shared__ __align__(16) float s11[TPB * 27];
    __shared__ __align__(16) float s01[TPB * 3];
    __shared__ __align__(16) float s10[TPB * 3];

    const int tid = threadIdx.x;
    const int base = blockIdx.x * TPB;
    const int nE = (E - base < TPB) ? (E - base) : TPB;

    if (nE == TPB) {
        // full slab: float4-coalesced (base*27*4B and base*3*4B are 16B-mult)
        const f4* s11s = (const f4*)(wj11 + (size_t)base * 27);
        f4* s11d = (f4*)s11;
#pragma unroll 2
        for (int i = tid; i < TPB * 27 / 4; i += TPB) s11d[i] = s11s[i];
        const f4* s01s = (const f4*)(wj01 + (size_t)base * 3);
        const f4* s10s = (const f4*)(wj10 + (size_t)base * 3);
        f4* s01d = (f4*)s01;
        f4* s10d = (f4*)s10;
        for (int i = tid; i < TPB * 3 / 4; i += TPB) {
            s01d[i] = s01s[i];
            s10d[i] = s10s[i];
        }
    } else {
        for (int i = tid; i < nE * 27; i += TPB) s11[i] = wj11[(size_t)base * 27 + i];
        for (int i = tid; i < nE * 3; i += TPB) {
            s01[i] = wj01[(size_t)base * 3 + i];
            s10[i] = wj10[(size_t)base * 3 + i];
        }
    }
    __syncthreads();

    const int e = base + tid;
    if (e >= E) return;

    const float* my11 = s11 + tid * 27;
    const float* my01 = s01 + tid * 3;
    const float* my10 = s10 + tid * 3;

    const int uu = u[e];
    const int vv = v[e];

    const f2 f0u = *(const f2*)(f0 + (size_t)uu * 2);
    const f2 f0v2 = *(const f2*)(f0 + (size_t)vv * 2);
    const float f0v0 = f0v2.x;
    const float f0v1 = f0v2.y;
    // f1 row: 6 floats, 8B-aligned -> three float2 loads
    const f2 f1a = *(const f2*)(f1 + (size_t)vv * 6);
    const f2 f1b = *(const f2*)(f1 + (size_t)vv * 6 + 2);
    const f2 f1c = *(const f2*)(f1 + (size_t)vv * 6 + 4);
    float f1v[2][3];
    f1v[0][0] = f1a.x; f1v[0][1] = f1a.y; f1v[0][2] = f1b.x;
    f1v[1][0] = f1b.y; f1v[1][1] = f1c.x; f1v[1][2] = f1c.y;

    const float vec0 = f0u.x * f0v0;
    const float vec1 = f0u.y * f0v1;
    const float vec2 = dist[e];

    float acc0[2] = {0.f, 0.f};
    float acc1[2][3] = {{0.f, 0.f, 0.f}, {0.f, 0.f, 0.f}};

    // ---- MLP i=0: (l=0,k=0) ----
    {
        f2 h2[8];
        radial_h2(vec0, vec1, vec2, rW1 + 0 * 48, rb1 + 0 * 16, g1 + 0 * 16,
                  be1 + 0 * 16, rW2 + 0 * 256, rb2 + 0 * 16, g2 + 0 * 16,
                  be2 + 0 * 16, h2);
        f2 p0, p1;
        layer3_4(h2, W3_00, b3_00, p0, p1);
        const float w = wj00[e];
        acc0[0] += w * (p0.x * f0v0 + p0.y * f0v1);
        acc0[1] += w * (p1.x * f0v0 + p1.y * f0v1);
    }
    // ---- MLP i=1: (l=0,k=1) ----
    {
        f2 h2[8];
        radial_h2(vec0, vec1, vec2, rW1 + 1 * 48, rb1 + 1 * 16, g1 + 1 * 16,
                  be1 + 1 * 16, rW2 + 1 * 256, rb2 + 1 * 16, g2 + 1 * 16,
                  be2 + 1 * 16, h2);
        f2 p0, p1;
        layer3_4(h2, W3_01, b3_01, p0, p1);
        const float w0 = my01[0];
        const float w1 = my01[1];
        const float w2 = my01[2];
        const float s0 = w0 * f1v[0][0] + w1 * f1v[0][1] + w2 * f1v[0][2];
        const float s1 = w0 * f1v[1][0] + w1 * f1v[1][1] + w2 * f1v[1][2];
        acc0[0] += p0.x * s0 + p0.y * s1;
        acc0[1] += p1.x * s0 + p1.y * s1;
    }
    // ---- MLP i=2: (l=1,k=0) ----
    {
        f2 h2[8];
        radial_h2(vec0, vec1, vec2, rW1 + 2 * 48, rb1 + 2 * 16, g1 + 2 * 16,
                  be1 + 2 * 16, rW2 + 2 * 256, rb2 + 2 * 16, g2 + 2 * 16,
                  be2 + 2 * 16, h2);
        f2 p0, p1;
        layer3_4(h2, W3_10, b3_10, p0, p1);
        const float t0 = p0.x * f0v0 + p0.y * f0v1;
        const float t1 = p1.x * f0v0 + p1.y * f0v1;
#pragma unroll
        for (int m = 0; m < 3; ++m) {
            const float w = my10[m];
            acc1[0][m] += w * t0;
            acc1[1][m] += w * t1;
        }
    }
    // ---- MLP i=3: (l=1,k=1): layer3 computed per j-row, consumed at once ----
    {
        f2 h2[8];
        radial_h2(vec0, vec1, vec2, rW1 + 3 * 48, rb1 + 3 * 16, g1 + 3 * 16,
                  be1 + 3 * 16, rW2 + 3 * 256, rb2 + 3 * 16, g2 + 3 * 16,
                  be2 + 3 * 16, h2);
#pragma unroll
        for (int j = 0; j < 3; ++j) {
            // p0 = {R[j,o0,i0], R[j,o0,i1]}, p1 = {R[j,o1,i0], R[j,o1,i1]}
            f2 p0 = *(const f2*)(b3_11 + j * 4);
            f2 p1 = *(const f2*)(b3_11 + j * 4 + 2);
#pragma unroll
            for (int c = 0; c < 16; ++c) {
                const f2 hc = splat(get16(h2, c));
                p0 = fma2(hc, *(const f2*)(W3_11 + c * 12 + j * 4), p0);
                p1 = fma2(hc, *(const f2*)(W3_11 + c * 12 + j * 4 + 2), p1);
            }
#pragma unroll
            for (int m = 0; m < 3; ++m) {
                const float w0 = my11[j * 9 + m * 3 + 0];
                const float w1 = my11[j * 9 + m * 3 + 1];
                const float w2 = my11[j * 9 + m * 3 + 2];
                const float B0 =
                    w0 * f1v[0][0] + w1 * f1v[0][1] + w2 * f1v[0][2];
                const float B1 =
                    w0 * f1v[1][0] + w1 * f1v[1][1] + w2 * f1v[1][2];
                acc1[0][m] += p0.x * B0 + p0.y * B1;
                acc1[1][m] += p1.x * B0 + p1.y * B1;
            }
        }
    }

    // ---- q[v] . k_feat ----  wq[d][o][i] = wq[d*4+o*2+i]
    float dot = 0.f;
    {
        const float q00 = wq[0] * f0v0 + wq[1] * f0v1;
        const float q01 = wq[2] * f0v0 + wq[3] * f0v1;
        dot += q00 * acc0[0] + q01 * acc0[1];
#pragma unroll
        for (int m = 0; m < 3; ++m) {
            const float q1m0 = wq[4] * f1v[0][m] + wq[5] * f1v[1][m];
            const float q1m1 = wq[6] * f1v[0][m] + wq[7] * f1v[1][m];
            dot += q1m0 * acc1[0][m] + q1m1 * acc1[1][m];
        }
    }

    out[e] = dot;
    atomicAdd(&ssum[vv], exp((double)dot));
}

__global__ void norm_kernel(float* __restrict__ out, const int* __restrict__ v,
                            const double* __restrict__ ssum, int E) {
    int e = blockIdx.x * blockDim.x + threadIdx.x;
    if (e >= E) return;
    const double t = exp((double)out[e]);
    out[e] = (float)(t / ssum[v[e]]);
}

extern "C" void kernel_launch(void* const* d_in, const int* in_sizes, int n_in,
                              void* d_out, int out_size, void* d_ws,
                              size_t ws_size, hipStream_t stream) {
    const float* f0 = (const float*)d_in[0];
    const float* f1 = (const float*)d_in[1];
    const float* dist = (const float*)d_in[2];
    const int* u = (const int*)d_in[3];
    const int* v = (const int*)d_in[4];
    const float* wq = (const float*)d_in[5];
    const float* wj00 = (const float*)d_in[6];
    const float* wj01 = (const float*)d_in[7];
    const float* wj10 = (const float*)d_in[8];
    const float* wj11 = (const float*)d_in[9];
    const float* rW1 = (const float*)d_in[10];
    const float* rb1 = (const float*)d_in[11];
    const float* g1 = (const float*)d_in[12];
    const float* be1 = (const float*)d_in[13];
    const float* rW2 = (const float*)d_in[14];
    const float* rb2 = (const float*)d_in[15];
    const float* g2 = (const float*)d_in[16];
    const float* be2 = (const float*)d_in[17];
    const float* W3_00 = (const float*)d_in[18];
    const float* b3_00 = (const float*)d_in[19];
    const float* W3_01 = (const float*)d_in[20];
    const float* b3_01 = (const float*)d_in[21];
    const float* W3_10 = (const float*)d_in[22];
    const float* b3_10 = (const float*)d_in[23];
    const float* W3_11 = (const float*)d_in[24];
    const float* b3_11 = (const float*)d_in[25];

    const int N = in_sizes[0] / 2;  // f0 is [N,2,1]
    const int E = in_sizes[2];      // dist is [E]

    double* ssum = (double*)d_ws;
    float* out = (float*)d_out;

    const int ge = (E + TPB - 1) / TPB;

    hipMemsetAsync(ssum, 0, (size_t)N * sizeof(double), stream);
    edge_kernel<<<ge, TPB, 0, stream>>>(
        f0, f1, dist, u, v, wq, wj00, wj01, wj10, wj11, rW1, rb1, g1, be1, rW2,
        rb2, g2, be2, W3_00, b3_00, W3_01, b3_01, W3_10, b3_10, W3_11, b3_11,
        out, ssum, E);
    norm_kernel<<<ge, TPB, 0, stream>>>(out, v, ssum, E);
}